// Round 3
// baseline (266.739 us; speedup 1.0000x reference)
//
#include <hip/hip_runtime.h>

// FeatureMagnet r17: 6-dispatch fused pipeline, WIDE blocks.
// r16 post-mortem: k_ffn=47.8us at 7.7% occupancy (192 blocks x 4 waves = 3
// waves/CU) -> latency-bound, all pipes idle. r17 re-tiles the three fused
// row-kernels to 1024-thread / 16-wave blocks over 8 rows:
//   k_fmlp: 264 blocks (was 144 -> half the CUs idle)
//   k_oln : 384 blocks (was 192)
//   k_ffn : 384 blocks (was 192)
// 8-row blocks replicate A-rows via (qi&7) in the MFMA fragment and gate
// stores with quad<2 (MFMA waste irrelevant at 2.4% util; TLP is the lever).
// LE=LA=2048, C=256, H=8, DH=32, DF=1024, n_remain=1024, Lq=3072, Lk=4096.

#define LE 2048
#define LA 2048
#define CDIM 256
#define HN 8
#define DH 32
#define DFF 1024
#define NREM 1024
#define LQC 3072
#define LKC 4096
#define KSPLIT 8
#define NIT (LKC / KSPLIT / 64)   // 8 iterations of 64 keys

typedef unsigned short u16;
typedef unsigned int u32;
typedef __attribute__((ext_vector_type(8))) short bf16x8;
typedef __attribute__((ext_vector_type(2))) _Float16 f16x2;
typedef __attribute__((ext_vector_type(4))) float f32x4;

#define MFMA __builtin_amdgcn_mfma_f32_16x16x32_bf16

__device__ __forceinline__ u32 pk_bf16(float a, float b) {
    u32 ua = (__builtin_bit_cast(u32, a) + 0x8000u) >> 16;
    u32 ub = (__builtin_bit_cast(u32, b) + 0x8000u) >> 16;
    return ua | (ub << 16);
}
__device__ __forceinline__ u16 bf16_1(float a) {
    return (u16)((__builtin_bit_cast(u32, a) + 0x8000u) >> 16);
}
__device__ __forceinline__ float fast_exp2(float x) {
    return __builtin_amdgcn_exp2f(x);
}
__device__ __forceinline__ bf16x8 ld_pack8(const float* p) {
    float4 f0 = *(const float4*)p;
    float4 f1 = *(const float4*)(p + 4);
    union { u32 u[4]; bf16x8 v; } o;
    o.u[0] = pk_bf16(f0.x, f0.y); o.u[1] = pk_bf16(f0.z, f0.w);
    o.u[2] = pk_bf16(f1.x, f1.y); o.u[3] = pk_bf16(f1.z, f1.w);
    return o.v;
}

struct WPtrs { const float* p[7]; };
__constant__ __device__ const int woff[8] = {0, 131072, 196608, 262144,
                                             458752, 524288, 786432, 1048576};

// --- k_prep: block0 = hash-join match + unmatched scan; blocks 1..128 =
// --- weight f32->bf16 cvt; blocks 129..256 = kv staging. ----------------
__global__ __launch_bounds__(1024) void k_prep(const int* __restrict__ pos_ego,
                                               const int* __restrict__ pos_agent,
                                               int* __restrict__ afe,
                                               int* __restrict__ matched,
                                               int* __restrict__ remain,
                                               const float* __restrict__ x_ego,
                                               const float* __restrict__ x_agent,
                                               WPtrs wp, u16* __restrict__ wb,
                                               u16* __restrict__ kv_b) {
    const int b = blockIdx.x;
    const int t = threadIdx.x;
    if (b == 0) {
        __shared__ int keyA[4096], valA[4096], keyE[4096];
        __shared__ int unm[2048];
#pragma unroll
        for (int i = 0; i < 4; ++i) { keyA[t + i * 1024] = -1; keyE[t + i * 1024] = -1; }
        __syncthreads();
#pragma unroll
        for (int i = 0; i < 2; ++i) {
            int a = t + i * 1024;
            int p = pos_agent[a];
            u32 h = ((u32)p * 2654435761u) >> 20;
            while (true) {
                int prev = atomicCAS(&keyA[h], -1, p);
                if (prev == -1) { valA[h] = a; break; }
                h = (h + 1) & 4095;
            }
            int e = t + i * 1024;
            int pe = pos_ego[e];
            u32 he = ((u32)pe * 2654435761u) >> 20;
            while (true) {
                int prev = atomicCAS(&keyE[he], -1, pe);
                if (prev == -1) break;
                he = (he + 1) & 4095;
            }
        }
        __syncthreads();
#pragma unroll
        for (int i = 0; i < 2; ++i) {
            int e = t + i * 1024;
            int p = pos_ego[e];
            u32 h = ((u32)p * 2654435761u) >> 20;
            int idx = 0, fnd = 0;
            while (true) {
                int k = keyA[h];
                if (k == p) { idx = valA[h]; fnd = 1; break; }
                if (k == -1) break;
                h = (h + 1) & 4095;
            }
            afe[e] = idx;
            matched[e] = fnd;
            int a = t + i * 1024;
            int pa_ = pos_agent[a];
            u32 ha = ((u32)pa_ * 2654435761u) >> 20;
            int fnd2 = 0;
            while (true) {
                int k = keyE[ha];
                if (k == pa_) { fnd2 = 1; break; }
                if (k == -1) break;
                ha = (ha + 1) & 4095;
            }
            unm[a] = !fnd2;
        }
        __syncthreads();
        int f0 = unm[2 * t], f1 = unm[2 * t + 1];
        int cnt = f0 + f1;
        valA[t] = cnt;
        __syncthreads();
        for (int off = 1; off < 1024; off <<= 1) {
            int v = (t >= off) ? valA[t - off] : 0;
            __syncthreads();
            valA[t] += v;
            __syncthreads();
        }
        int pos = valA[t] - cnt;
        if (f0 && pos < NREM) remain[pos] = 2 * t;
        if (f1 && pos + f0 < NREM) remain[pos + f0] = 2 * t + 1;
    } else if (b <= 128) {
        int g = ((b - 1) * 1024 + t) * 8;
        int s = 0;
#pragma unroll
        for (int i = 1; i < 7; ++i) s += (g >= woff[i]);
        const float* src = wp.p[s] + (g - woff[s]);
        float4 f0 = *(const float4*)(src);
        float4 f1 = *(const float4*)(src + 4);
        uint4 o;
        o.x = pk_bf16(f0.x, f0.y); o.y = pk_bf16(f0.z, f0.w);
        o.z = pk_bf16(f1.x, f1.y); o.w = pk_bf16(f1.z, f1.w);
        *(uint4*)(wb + g) = o;
    } else {
        int tt = (b - 129) * 1024 + t;
        int j = tt >> 5, c8 = tt & 31;
        const float* src = (j < LE) ? (x_ego + (size_t)j * CDIM)
                                    : (x_agent + (size_t)(j - LE) * CDIM);
        float4 f0 = *(const float4*)(src + c8 * 8);
        float4 f1 = *(const float4*)(src + c8 * 8 + 4);
        uint4 o;
        o.x = pk_bf16(f0.x, f0.y); o.y = pk_bf16(f0.z, f0.w);
        o.z = pk_bf16(f1.x, f1.y); o.w = pk_bf16(f1.z, f1.w);
        *(uint4*)(kv_b + (size_t)j * CDIM + c8 * 8) = o;
    }
}

// --- k_fmlp: fused 3-layer fusion MLP, 8 rows/block, 16 waves, h1/h2 LDS --
// blocks 0..255: MLP rows 0..2047; blocks 256..263: gather rows 2048..3071.
__global__ __launch_bounds__(1024) void k_fmlp(const float* __restrict__ x_ego,
                                               const float* __restrict__ x_agent,
                                               const int* __restrict__ afe,
                                               const int* __restrict__ matched,
                                               const int* __restrict__ remain,
                                               const u16* __restrict__ Wf1_b,
                                               const u16* __restrict__ Wf2_b,
                                               const u16* __restrict__ Wf3_b,
                                               const float* __restrict__ bf1,
                                               const float* __restrict__ bf2,
                                               const float* __restrict__ bf3,
                                               float* __restrict__ qbuf,
                                               u16* __restrict__ qbuf_b) {
    const int blk = blockIdx.x;
    const int tid = threadIdx.x;
    if (blk >= 256) {  // gather blocks: 8 blocks x 128 rows
        int rb = (blk - 256) * 128 + (tid >> 3);
        int row = LE + rb;
        int col = (tid & 7) * 32;
        int idx = remain[rb];
        idx = min(max(idx, 0), LA - 1);
        const float* src = x_agent + (size_t)idx * CDIM + col;
        float* dq = qbuf + (size_t)row * CDIM + col;
        u16* db = qbuf_b + (size_t)row * CDIM + col;
#pragma unroll
        for (int i = 0; i < 8; ++i) {
            float4 v = *(const float4*)(src + i * 4);
            *(float4*)(dq + i * 4) = v;
            *(uint2*)(db + i * 4) = make_uint2(pk_bf16(v.x, v.y), pk_bf16(v.z, v.w));
        }
        return;
    }
    __shared__ u16 h1[8 * 256];  // XOR-swizzled, 4KB
    __shared__ u16 h2[8 * 256];
    const int w = tid >> 6, lane = tid & 63, quad = lane >> 4, qi = lane & 15;
    const int R0 = blk * 8;
    const int ar = qi & 7;          // replicated A-row
    const int col = w * 16 + qi;    // this lane's output column (0..255)
    // stage 1: h1 = relu([x_ego | x_agent[afe]] @ Wf1^T + bf1)
    {
        const float* pe = x_ego + (size_t)(R0 + ar) * CDIM + quad * 8;
        const float* pg = x_agent + (size_t)afe[R0 + ar] * CDIM + quad * 8;
        f32x4 acc = {};
        const u16* pb = Wf1_b + (size_t)col * 512 + quad * 8;
#pragma unroll
        for (int kk = 0; kk < 256; kk += 32)
            acc = MFMA(ld_pack8(pe + kk), *(const bf16x8*)(pb + kk), acc, 0, 0, 0);
#pragma unroll
        for (int kk = 0; kk < 256; kk += 32)
            acc = MFMA(ld_pack8(pg + kk), *(const bf16x8*)(pb + 256 + kk), acc, 0, 0, 0);
        if (quad < 2) {
            float bs = bf1[col];
#pragma unroll
            for (int r = 0; r < 4; ++r) {
                int row = quad * 4 + r;
                float vv = fmaxf(acc[r] + bs, 0.f);
                int byte = (row * 512 + col * 2) ^ (row << 4);
                *(u16*)((char*)h1 + byte) = bf16_1(vv);
            }
        }
    }
    __syncthreads();
    // stage 2: h2 = relu(h1 @ Wf2^T + bf2)
    {
        f32x4 acc = {};
        const u16* pb = Wf2_b + (size_t)col * 256 + quad * 8;
#pragma unroll
        for (int kk = 0; kk < 256; kk += 32) {
            int byte = (ar * 512 + (kk + quad * 8) * 2) ^ (ar << 4);
            acc = MFMA(*(const bf16x8*)((char*)h1 + byte),
                       *(const bf16x8*)(pb + kk), acc, 0, 0, 0);
        }
        if (quad < 2) {
            float bs = bf2[col];
#pragma unroll
            for (int r = 0; r < 4; ++r) {
                int row = quad * 4 + r;
                float vv = fmaxf(acc[r] + bs, 0.f);
                int byte = (row * 512 + col * 2) ^ (row << 4);
                *(u16*)((char*)h2 + byte) = bf16_1(vv);
            }
        }
    }
    __syncthreads();
    // stage 3: fused = h2 @ Wf3^T + bf3; select(matched); emit qbuf/qbuf_b
    {
        f32x4 acc = {};
        const u16* pb = Wf3_b + (size_t)col * 256 + quad * 8;
#pragma unroll
        for (int kk = 0; kk < 256; kk += 32) {
            int byte = (ar * 512 + (kk + quad * 8) * 2) ^ (ar << 4);
            acc = MFMA(*(const bf16x8*)((char*)h2 + byte),
                       *(const bf16x8*)(pb + kk), acc, 0, 0, 0);
        }
        if (quad < 2) {
            float bs = bf3[col];
#pragma unroll
            for (int r = 0; r < 4; ++r) {
                int row = R0 + quad * 4 + r;
                float vv = acc[r] + bs;
                if (!matched[row]) vv = x_ego[(size_t)row * CDIM + col];
                qbuf[(size_t)row * CDIM + col] = vv;
                qbuf_b[(size_t)row * CDIM + col] = bf16_1(vv);
            }
        }
    }
}

// --------------------------- fused QKV projection (one dispatch) -----------
__global__ __launch_bounds__(256) void k_qkv(const u16* __restrict__ qbuf_b,
                                             const u16* __restrict__ kv_b,
                                             const u16* __restrict__ Wq,
                                             const u16* __restrict__ Wkv,
                                             const float* __restrict__ bqkv,
                                             u16* __restrict__ qb,
                                             u16* __restrict__ kbp,
                                             u16* __restrict__ vtb,
                                             float qscale) {
    int b;
    {
        int p = blockIdx.x;  // grid = 704 = 8 * 88
        int c = p & 7, s = p >> 3;
        b = c * 88 + s;
    }
    const u16 *A, *B;
    const float* bias;
    int bm, bn, mode;
    if (b < 192) {
        A = qbuf_b; B = Wq; bias = bqkv;
        bm = (b >> 2) * 64; bn = (b & 3) * 64; mode = 0;
    } else {
        int c = b - 192;
        A = kv_b; B = Wkv; bias = bqkv + 256;
        bm = (c >> 3) * 64; bn = (c & 7) * 64; mode = 1;
    }
    const int tid = threadIdx.x;
    const int w = tid >> 6, lane = tid & 63;
    const int quad = lane >> 4, qi = lane & 15;
    const int wm = w >> 1, wn = w & 1;
    const int K = 256;

    const u16* pa0 = A + (size_t)(bm + wm * 32 + qi) * K + quad * 8;
    const u16* pa1 = pa0 + (size_t)16 * K;
    const u16* pb0 = B + (size_t)(bn + wn * 32 + qi) * K + quad * 8;
    const u16* pb1 = pb0 + (size_t)16 * K;

    f32x4 acc00 = {0.f, 0.f, 0.f, 0.f}, acc01 = {0.f, 0.f, 0.f, 0.f};
    f32x4 acc10 = {0.f, 0.f, 0.f, 0.f}, acc11 = {0.f, 0.f, 0.f, 0.f};
#pragma unroll 4
    for (int k = 0; k < 256; k += 32) {
        bf16x8 a0 = *(const bf16x8*)(pa0 + k);
        bf16x8 a1 = *(const bf16x8*)(pa1 + k);
        bf16x8 b0 = *(const bf16x8*)(pb0 + k);
        bf16x8 b1 = *(const bf16x8*)(pb1 + k);
        acc00 = MFMA(a0, b0, acc00, 0, 0, 0);
        acc01 = MFMA(a0, b1, acc01, 0, 0, 0);
        acc10 = MFMA(a1, b0, acc10, 0, 0, 0);
        acc11 = MFMA(a1, b1, acc11, 0, 0, 0);
    }
#pragma unroll
    for (int i = 0; i < 2; ++i) {
#pragma unroll
        for (int j = 0; j < 2; ++j) {
            f32x4 acc = (i == 0) ? (j == 0 ? acc00 : acc01) : (j == 0 ? acc10 : acc11);
            int n = bn + wn * 32 + j * 16 + qi;
            int mbase = bm + wm * 32 + i * 16 + quad * 4;
            float bs = bias[n];
            float v[4];
#pragma unroll
            for (int r = 0; r < 4; ++r) v[r] = acc[r] + bs;
            if (mode == 0) {
#pragma unroll
                for (int r = 0; r < 4; ++r)
                    qb[(size_t)(mbase + r) * 256 + n] = bf16_1(v[r] * qscale);
            } else if (n < 256) {
#pragma unroll
                for (int r = 0; r < 4; ++r)
                    kbp[(size_t)(mbase + r) * 256 + n] = bf16_1(v[r]);
            } else {
                ushort4 o4;
                o4.x = bf16_1(v[0]); o4.y = bf16_1(v[1]);
                o4.z = bf16_1(v[2]); o4.w = bf16_1(v[3]);
                *(ushort4*)(vtb + (size_t)(n - 256) * LKC + mbase) = o4;
            }
        }
    }
}

// --------------------------- MFMA attention, LDS-staged K/V tiles ----------
__global__ __launch_bounds__(256) void attn_mfma(const u16* __restrict__ qb,
                                                 const u16* __restrict__ kb,
                                                 const u16* __restrict__ vtb,
                                                 float* __restrict__ Pl,
                                                 u16* __restrict__ Pacc) {
    __shared__ u16 Kt[2][64 * 32];
    __shared__ u16 Vt[2][32 * 64];
    __shared__ u16 plds[4][16 * 64];
    const int tid = threadIdx.x;
    const int w = tid >> 6, lane = tid & 63;
    const int quad = lane >> 4, qi = lane & 15;
    int h, ks, q0;
    {
        int p = (blockIdx.z * gridDim.y + blockIdx.y) * gridDim.x + blockIdx.x;
        int c = p & 7, s = p >> 3;
        int l = c * 384 + s;  // 3072 / 8
        int qblk = l % 48;
        int hk = l / 48;
        h = hk & 7; ks = hk >> 3;
        q0 = qblk * 64 + w * 16;
    }

    bf16x8 qf = *(const bf16x8*)(qb + (size_t)(q0 + qi) * CDIM + h * DH + quad * 8);

    f32x4 O0 = {0.f, 0.f, 0.f, 0.f}, O1 = {0.f, 0.f, 0.f, 0.f};
    float lsum = 0.f;

    const int krow = w * 16 + (lane >> 2), kcp = lane & 3;
    const int kc = kcp ^ (krow & 3);
    const u16* kg0 = kb + (size_t)krow * CDIM + h * DH + kc * 8;
    const int kdst = krow * 32 + kcp * 8;
    const int vd = w * 8 + (lane >> 3), vcp = lane & 7;
    const int vc = vcp ^ (vd & 7);
    const u16* vg0 = vtb + (size_t)(h * DH + vd) * LKC + vc * 8;
    const int vdst = vd * 64 + vcp * 8;

    const int ka0 = qi * 32 + ((quad ^ (qi & 3)) << 3);
    const int v00o = qi * 64 + ((quad ^ (qi & 7)) << 3);
    const int v01o = qi * 64 + (((quad + 4) ^ (qi & 7)) << 3);
    const int swz = (qi & 7);
    const int rd0 = qi * 64 + ((quad ^ swz) << 3);
    const int rd1 = qi * 64 + (((4 + quad) ^ swz) << 3);
    const int half = (quad & 1) << 2;

    int kt = ks * (LKC / KSPLIT);
    {
        bf16x8 kr = *(const bf16x8*)(kg0 + (size_t)kt * CDIM);
        bf16x8 vr = *(const bf16x8*)(vg0 + kt);
        *(bf16x8*)&Kt[0][kdst] = kr;
        *(bf16x8*)&Vt[0][vdst] = vr;
    }
    int buf = 0;
    for (int it = 0; it < NIT; ++it, kt += 64) {
        __syncthreads();
        bf16x8 knext, vnext;
        const bool more = (it + 1 < NIT);
        if (more) {
            knext = *(const bf16x8*)(kg0 + (size_t)(kt + 64) * CDIM);
            vnext = *(const bf16x8*)(vg0 + kt + 64);
        }

        bf16x8 a0 = *(const bf16x8*)&Kt[buf][ka0];
        bf16x8 a1 = *(const bf16x8*)&Kt[buf][ka0 + 16 * 32];
        bf16x8 a2 = *(const bf16x8*)&Kt[buf][ka0 + 32 * 32];
        bf16x8 a3 = *(const bf16x8*)&Kt[buf][ka0 + 48 * 32];
        f32x4 z = {0.f, 0.f, 0.f, 0.f};
        f32x4 s0 = MFMA(a0, qf, z, 0, 0, 0);
        f32x4 s1 = MFMA(a1, qf, z, 0, 0, 0);
        f32x4 s2 = MFMA(a2, qf, z, 0, 0, 0);
        f32x4 s3 = MFMA(a3, qf, z, 0, 0, 0);

        float p0[4], p1[4], p2[4], p3[4];
#pragma unroll
        for (int r = 0; r < 4; ++r) {
            p0[r] = fast_exp2(s0[r]); p1[r] = fast_exp2(s1[r]);
            p2[r] = fast_exp2(s2[r]); p3[r] = fast_exp2(s3[r]);
            lsum += p0[r] + p1[r] + p2[r] + p3[r];
        }

        u16* pb = &plds[w][0];
#pragma unroll
        for (int t2 = 0; t2 < 4; ++t2) {
            int jg = t2 * 2 + (quad >> 1);
            int off = qi * 64 + ((jg ^ swz) << 3) + half;
            uint2 pw;
            float* pp = (t2 == 0) ? p0 : (t2 == 1) ? p1 : (t2 == 2) ? p2 : p3;
            pw.x = pk_bf16(pp[0], pp[1]);
            pw.y = pk_bf16(pp[2], pp[3]);
            *(uint2*)&pb[off] = pw;
        }
        bf16x8 pa0 = *(bf16x8*)&pb[rd0];
        bf16x8 pa1 = *(bf16x8*)&pb[rd1];

        bf16x8 v00 = *(const bf16x8*)&Vt[buf][v00o];
        bf16x8 v01 = *(const bf16x8*)&Vt[buf][v01o];
        bf16x8 v10 = *(const bf16x8*)&Vt[buf][v00o + 16 * 64];
        bf16x8 v11 = *(const bf16x8*)&Vt[buf][v01o + 16 * 64];
        O0 = MFMA(pa0, v00, O0, 0, 0, 0);
        O0 = MFMA(pa1, v01, O0, 0, 0, 0);
        O1 = MFMA(pa0, v10, O1, 0, 0, 0);
        O1 = MFMA(pa1, v11, O1, 0, 0, 0);

        if (more) {
            *(bf16x8*)&Kt[buf ^ 1][kdst] = knext;
            *(bf16x8*)&Vt[buf ^ 1][vdst] = vnext;
        }
        buf ^= 1;
    }

    lsum += __shfl_xor(lsum, 16, 64);
    lsum += __shfl_xor(lsum, 32, 64);

    int pbase = (h * KSPLIT + ks) * LQC + q0;
    if (quad == 0) Pl[pbase + qi] = lsum;
#pragma unroll
    for (int r = 0; r < 4; ++r) {
        int q = quad * 4 + r;
        u16* pa = Pacc + (size_t)(pbase + q) * 32;
        pa[qi] = __builtin_bit_cast(u16, (_Float16)O0[r]);
        pa[16 + qi] = __builtin_bit_cast(u16, (_Float16)O1[r]);
    }
}

// --- k_oln: combine + out-proj + residual + LN1; 8 rows, 16 waves ---------
__global__ __launch_bounds__(1024) void k_oln(const float* __restrict__ Pl,
                                              const u16* __restrict__ Pacc,
                                              const u16* __restrict__ Wo_b,
                                              const float* __restrict__ bo,
                                              const float* __restrict__ qbuf,
                                              const float* __restrict__ g1,
                                              const float* __restrict__ be1,
                                              float* __restrict__ yq,
                                              u16* __restrict__ yq_b) {
    __shared__ u16 At[8 * 256];      // combined attn out, bf16, XOR-swizzled
    __shared__ float red[8][16][2];  // [row][wave][(s,sq)]
    const int tid = threadIdx.x;
    const int R0 = blockIdx.x * 8;
    // phase A: KSPLIT combine -> At (thread = (row, 2 cols))
    {
        int row = tid >> 7, cg = tid & 127;
        int h = cg >> 4, dh2 = (cg & 15) * 2;
        int r = R0 + row;
        float L = 0.f, o0 = 0.f, o1 = 0.f;
#pragma unroll
        for (int ks = 0; ks < 8; ++ks) {
            size_t pidx = (size_t)(h * 8 + ks) * LQC + r;
            L += Pl[pidx];
            f16x2 v = *(const f16x2*)(Pacc + pidx * 32 + dh2);
            o0 += (float)v[0]; o1 += (float)v[1];
        }
        float invL = 1.0f / L;
        int col = h * 32 + dh2;
        int byte = (row * 512 + col * 2) ^ (row << 4);
        *(u32*)((char*)At + byte) = pk_bf16(o0 * invL, o1 * invL);
    }
    __syncthreads();
    // phase B: out-proj GEMM (K=256), wave w covers cols w*16..w*16+15
    const int w = tid >> 6, lane = tid & 63, quad = lane >> 4, qi = lane & 15;
    const int ar = qi & 7;
    const int col = w * 16 + qi;
    f32x4 acc = {};
    const u16* pb = Wo_b + (size_t)col * 256 + quad * 8;
#pragma unroll
    for (int kk = 0; kk < 256; kk += 32) {
        int byte = (ar * 512 + (kk + quad * 8) * 2) ^ (ar << 4);
        acc = MFMA(*(const bf16x8*)((char*)At + byte),
                   *(const bf16x8*)(pb + kk), acc, 0, 0, 0);
    }
    // phase C: +bias +residual, LN1, emit yq/yq_b
    float v[4], s[4], sq[4];
    float bs = bo[col];
#pragma unroll
    for (int r = 0; r < 4; ++r) {
        int row = R0 + (quad & 1) * 4 + r;   // in-range for all quads
        float x = acc[r] + bs + qbuf[(size_t)row * CDIM + col];
        v[r] = x; s[r] = x; sq[r] = x * x;
    }
#pragma unroll
    for (int off = 1; off < 16; off <<= 1)
#pragma unroll
        for (int r = 0; r < 4; ++r) {
            s[r] += __shfl_xor(s[r], off, 64);
            sq[r] += __shfl_xor(sq[r], off, 64);
        }
    if (qi == 0 && quad < 2)
#pragma unroll
        for (int r = 0; r < 4; ++r) {
            red[quad * 4 + r][w][0] = s[r];
            red[quad * 4 + r][w][1] = sq[r];
        }
    __syncthreads();
    if (quad < 2) {
        float gg = g1[col], bb = be1[col];
#pragma unroll
        for (int r = 0; r < 4; ++r) {
            int rl = quad * 4 + r;
            float st = 0.f, sqt = 0.f;
#pragma unroll
            for (int ww = 0; ww < 16; ++ww) {
                st += red[rl][ww][0]; sqt += red[rl][ww][1];
            }
            float mean = st * (1.f / 256.f);
            float var = sqt * (1.f / 256.f) - mean * mean;
            float rstd = rsqrtf(var + 1e-5f);
            int row = R0 + rl;
            float o = (v[r] - mean) * rstd * gg + bb;
            yq[(size_t)row * CDIM + col] = o;
            yq_b[(size_t)row * CDIM + col] = bf16_1(o);
        }
    }
}

// --- k_ffn: FFN1 -> ReLU -> LDS -> FFN2 + residual + LN2; 8 rows, 16 waves -
__global__ __launch_bounds__(1024) void k_ffn(const u16* __restrict__ yq_b,
                                              const float* __restrict__ yq,
                                              const u16* __restrict__ W1_b,
                                              const float* __restrict__ b1,
                                              const u16* __restrict__ W2_b,
                                              const float* __restrict__ b2,
                                              const float* __restrict__ g2,
                                              const float* __restrict__ be2,
                                              float* __restrict__ out) {
    __shared__ u16 hT[8 * 1024];     // 16KB, XOR-swizzled
    __shared__ float red[8][16][2];
    const int tid = threadIdx.x;
    const int w = tid >> 6, lane = tid & 63, quad = lane >> 4, qi = lane & 15;
    const int R0 = blockIdx.x * 8;
    const int ar = qi & 7;
    // stage 1: h = relu(yq @ W1^T + b1), wave w covers h-cols w*64..w*64+63
    {
        const u16* pa = yq_b + (size_t)(R0 + ar) * 256 + quad * 8;
        f32x4 acc[4] = {};
        const u16* pb = W1_b + (size_t)(w * 64 + qi) * 256 + quad * 8;
#pragma unroll
        for (int kk = 0; kk < 256; kk += 32) {
            bf16x8 a = *(const bf16x8*)(pa + kk);
#pragma unroll
            for (int j = 0; j < 4; ++j)
                acc[j] = MFMA(a, *(const bf16x8*)(pb + (size_t)j * 16 * 256 + kk),
                              acc[j], 0, 0, 0);
        }
        if (quad < 2)
#pragma unroll
            for (int j = 0; j < 4; ++j) {
                int col = w * 64 + j * 16 + qi;
                float bs = b1[col];
#pragma unroll
                for (int r = 0; r < 4; ++r) {
                    int row = quad * 4 + r;
                    float vv = fmaxf(acc[j][r] + bs, 0.f);
                    int byte = (row * 2048 + col * 2) ^ (row << 4);
                    *(u16*)((char*)hT + byte) = bf16_1(vv);
                }
            }
    }
    __syncthreads();
    // stage 2: out = h @ W2^T + b2 + yq, LN2; wave w covers out-cols w*16..
    const int col = w * 16 + qi;
    f32x4 acc = {};
    const u16* pb = W2_b + (size_t)col * 1024 + quad * 8;
#pragma unroll 4
    for (int kk = 0; kk < 1024; kk += 32) {
        int byte = (ar * 2048 + (kk + quad * 8) * 2) ^ (ar << 4);
        acc = MFMA(*(const bf16x8*)((char*)hT + byte),
                   *(const bf16x8*)(pb + kk), acc, 0, 0, 0);
    }
    float v[4], s[4], sq[4];
    float bs = b2[col];
#pragma unroll
    for (int r = 0; r < 4; ++r) {
        int row = R0 + (quad & 1) * 4 + r;
        float x = acc[r] + bs + yq[(size_t)row * CDIM + col];
        v[r] = x; s[r] = x; sq[r] = x * x;
    }
#pragma unroll
    for (int off = 1; off < 16; off <<= 1)
#pragma unroll
        for (int r = 0; r < 4; ++r) {
            s[r] += __shfl_xor(s[r], off, 64);
            sq[r] += __shfl_xor(sq[r], off, 64);
        }
    if (qi == 0 && quad < 2)
#pragma unroll
        for (int r = 0; r < 4; ++r) {
            red[quad * 4 + r][w][0] = s[r];
            red[quad * 4 + r][w][1] = sq[r];
        }
    __syncthreads();
    if (quad < 2) {
        float gg = g2[col], bb = be2[col];
#pragma unroll
        for (int r = 0; r < 4; ++r) {
            int rl = quad * 4 + r;
            float st = 0.f, sqt = 0.f;
#pragma unroll
            for (int ww = 0; ww < 16; ++ww) {
                st += red[rl][ww][0]; sqt += red[rl][ww][1];
            }
            float mean = st * (1.f / 256.f);
            float var = sqt * (1.f / 256.f) - mean * mean;
            float rstd = rsqrtf(var + 1e-5f);
            int row = R0 + rl;
            out[(size_t)row * CDIM + col] = (v[r] - mean) * rstd * gg + bb;
        }
    }
}

// ------------------------------------------------------------------ launch --
extern "C" void kernel_launch(void* const* d_in, const int* in_sizes, int n_in,
                              void* d_out, int out_size, void* d_ws, size_t ws_size,
                              hipStream_t stream) {
    const float* x_ego = (const float*)d_in[0];
    const float* x_agent = (const float*)d_in[1];
    const float* Wf1 = (const float*)d_in[2];
    const float* bf1 = (const float*)d_in[3];
    const float* Wf2 = (const float*)d_in[4];
    const float* bf2 = (const float*)d_in[5];
    const float* Wf3 = (const float*)d_in[6];
    const float* bf3 = (const float*)d_in[7];
    const float* Wqkv = (const float*)d_in[8];
    const float* bqkv = (const float*)d_in[9];
    const float* Wo = (const float*)d_in[10];
    const float* bo = (const float*)d_in[11];
    const float* W1 = (const float*)d_in[12];
    const float* b1 = (const float*)d_in[13];
    const float* W2 = (const float*)d_in[14];
    const float* b2 = (const float*)d_in[15];
    const float* g1 = (const float*)d_in[16];
    const float* be1 = (const float*)d_in[17];
    const float* g2 = (const float*)d_in[18];
    const float* be2 = (const float*)d_in[19];
    const int* pos_ego = (const int*)d_in[20];
    const int* pos_agent = (const int*)d_in[21];

    float* ws = (float*)d_ws;
    size_t o = 0;
    float* qbuf = ws + o; o += 786432;
    float* yq = ws + o; o += 786432;
    float* Pl = ws + o; o += HN * KSPLIT * LQC;                       // 196608
    u16* Pacc = (u16*)(ws + o); o += (size_t)HN * KSPLIT * LQC * 16;  // f16
    u16* wb = (u16*)(ws + o); o += 524288;        // 1,048,576 u16
    u16* qbuf_b = (u16*)(ws + o); o += 393216;    // LQC*256
    u16* kv_b = (u16*)(ws + o); o += 524288;      // LKC*256
    u16* qb = (u16*)(ws + o); o += 393216;
    u16* kb = (u16*)(ws + o); o += 524288;
    u16* vtb = (u16*)(ws + o); o += 524288;
    u16* yq_b = (u16*)(ws + o); o += 393216;
    int* afe = (int*)(ws + o);
    int* matched = afe + LE;
    int* remain = matched + LE;

    const u16* Wf1_b = wb + 0;
    const u16* Wf2_b = wb + 131072;
    const u16* Wf3_b = wb + 196608;
    const u16* Wq_b = wb + 262144;
    const u16* Wkv_b = wb + 327680;
    const u16* Wo_b = wb + 458752;
    const u16* W1_b = wb + 524288;
    const u16* W2_b = wb + 786432;

    WPtrs wp;
    wp.p[0] = Wf1; wp.p[1] = Wf2; wp.p[2] = Wf3; wp.p[3] = Wqkv;
    wp.p[4] = Wo; wp.p[5] = W1; wp.p[6] = W2;

    // 1. match + scan co-dispatched with weight cvt + kv staging
    k_prep<<<257, 1024, 0, stream>>>(pos_ego, pos_agent, afe, matched, remain,
                                     x_ego, x_agent, wp, wb, kv_b);

    const float qscale = 0.17677669529663687f * 1.4426950408889634f;

    // 2. fused 3-layer fusion MLP + gather (264 wide blocks)
    k_fmlp<<<264, 1024, 0, stream>>>(x_ego, x_agent, afe, matched, remain,
                                     Wf1_b, Wf2_b, Wf3_b, bf1, bf2, bf3,
                                     qbuf, qbuf_b);

    // 3. fused QKV projections
    k_qkv<<<704, 256, 0, stream>>>(qbuf_b, kv_b, Wq_b, Wkv_b, bqkv, qb, kb, vtb, qscale);

    // 4. attention (KSPLIT=8)
    attn_mfma<<<dim3(LQC / 64, HN, KSPLIT), 256, 0, stream>>>(qb, kb, vtb, Pl, Pacc);

    // 5. combine + out-proj + residual + LN1 (384 wide blocks)
    k_oln<<<LQC / 8, 1024, 0, stream>>>(Pl, Pacc, Wo_b, bo, qbuf, g1, be1, yq, yq_b);

    // 6. FFN1 + FFN2 + residual + LN2 (384 wide blocks)
    k_ffn<<<LQC / 8, 1024, 0, stream>>>(yq_b, yq, W1_b, b1, W2_b, b2, g2, be2,
                                        (float*)d_out);
}

// Round 4
// 216.030 us; speedup vs baseline: 1.2347x; 1.2347x over previous
//
#include <hip/hip_runtime.h>

// FeatureMagnet r18: 8-dispatch pipeline — keep winning fusions, revert FFN.
//   k_prep  : hash-join match + scan + weight cvt + kv staging   (257 blk)
//   k_fmlp  : 3-layer fusion MLP (LDS h1/h2) + gather            (144 blk)
//   k_qkv   : fused Q/K/V projections                            (704 blk)
//   attn    : LDS-tiled flash attention, KSPLIT=8, f16 partials  (3072 blk)
//   k_oln   : KSPLIT combine + out-proj + residual + LN1         (192 blk)
//   ffn1    : gemm 64x64 tiles, relu, bf16 out                   (768 blk)
//   ffn2    : gemm 32x64 tiles, f32 out                          (384 blk)
//   ln2     : rowwise LN                                         (768 blk)
// r17 post-mortem: 8-row replication doubled MFMA+weight streaming; k_ffn
// 47.8->71.6us. r16 single-block-per-CU FFN fusion streams 1MB weights at
// 1 wave/SIMD -> latency-exposed. GEMM-shaped FFN with >=1.5 blocks/CU and
// distinct per-wave work is the fix.
// LE=LA=2048, C=256, H=8, DH=32, DF=1024, n_remain=1024, Lq=3072, Lk=4096.

#define LE 2048
#define LA 2048
#define CDIM 256
#define HN 8
#define DH 32
#define DFF 1024
#define NREM 1024
#define LQC 3072
#define LKC 4096
#define KSPLIT 8
#define NIT (LKC / KSPLIT / 64)   // 8 iterations of 64 keys

typedef unsigned short u16;
typedef unsigned int u32;
typedef __attribute__((ext_vector_type(8))) short bf16x8;
typedef __attribute__((ext_vector_type(2))) _Float16 f16x2;
typedef __attribute__((ext_vector_type(8))) _Float16 f16x8;
typedef __attribute__((ext_vector_type(4))) float f32x4;

#define MFMA __builtin_amdgcn_mfma_f32_16x16x32_bf16

__device__ __forceinline__ u32 pk_bf16(float a, float b) {
    u32 ua = (__builtin_bit_cast(u32, a) + 0x8000u) >> 16;
    u32 ub = (__builtin_bit_cast(u32, b) + 0x8000u) >> 16;
    return ua | (ub << 16);
}
__device__ __forceinline__ u16 bf16_1(float a) {
    return (u16)((__builtin_bit_cast(u32, a) + 0x8000u) >> 16);
}
__device__ __forceinline__ float fast_exp2(float x) {
    return __builtin_amdgcn_exp2f(x);
}
__device__ __forceinline__ bf16x8 ld_pack8(const float* p) {
    float4 f0 = *(const float4*)p;
    float4 f1 = *(const float4*)(p + 4);
    union { u32 u[4]; bf16x8 v; } o;
    o.u[0] = pk_bf16(f0.x, f0.y); o.u[1] = pk_bf16(f0.z, f0.w);
    o.u[2] = pk_bf16(f1.x, f1.y); o.u[3] = pk_bf16(f1.z, f1.w);
    return o.v;
}

// XCD-clustering remap for 64-row tiles
__device__ __forceinline__ void xcd_tile(int& bm, int& bn) {
    int gx = gridDim.x;
    int tot = gx * gridDim.y;
    int p = blockIdx.y * gx + blockIdx.x;
    int l = p;
    if (!(tot & 7)) { int c = p & 7, s = p >> 3; l = c * (tot >> 3) + s; }
    bm = (l / gx) * 64;
    bn = (l % gx) * 64;
}

struct WPtrs { const float* p[7]; };
__constant__ __device__ const int woff[8] = {0, 131072, 196608, 262144,
                                             458752, 524288, 786432, 1048576};

// --- k_prep: block0 = hash-join match + unmatched scan; blocks 1..128 =
// --- weight f32->bf16 cvt; blocks 129..256 = kv staging. ----------------
__global__ __launch_bounds__(1024) void k_prep(const int* __restrict__ pos_ego,
                                               const int* __restrict__ pos_agent,
                                               int* __restrict__ afe,
                                               int* __restrict__ matched,
                                               int* __restrict__ remain,
                                               const float* __restrict__ x_ego,
                                               const float* __restrict__ x_agent,
                                               WPtrs wp, u16* __restrict__ wb,
                                               u16* __restrict__ kv_b) {
    const int b = blockIdx.x;
    const int t = threadIdx.x;
    if (b == 0) {
        __shared__ int keyA[4096], valA[4096], keyE[4096];
        __shared__ int unm[2048];
#pragma unroll
        for (int i = 0; i < 4; ++i) { keyA[t + i * 1024] = -1; keyE[t + i * 1024] = -1; }
        __syncthreads();
#pragma unroll
        for (int i = 0; i < 2; ++i) {
            int a = t + i * 1024;
            int p = pos_agent[a];
            u32 h = ((u32)p * 2654435761u) >> 20;
            while (true) {
                int prev = atomicCAS(&keyA[h], -1, p);
                if (prev == -1) { valA[h] = a; break; }
                h = (h + 1) & 4095;
            }
            int e = t + i * 1024;
            int pe = pos_ego[e];
            u32 he = ((u32)pe * 2654435761u) >> 20;
            while (true) {
                int prev = atomicCAS(&keyE[he], -1, pe);
                if (prev == -1) break;
                he = (he + 1) & 4095;
            }
        }
        __syncthreads();
#pragma unroll
        for (int i = 0; i < 2; ++i) {
            int e = t + i * 1024;
            int p = pos_ego[e];
            u32 h = ((u32)p * 2654435761u) >> 20;
            int idx = 0, fnd = 0;
            while (true) {
                int k = keyA[h];
                if (k == p) { idx = valA[h]; fnd = 1; break; }
                if (k == -1) break;
                h = (h + 1) & 4095;
            }
            afe[e] = idx;
            matched[e] = fnd;
            int a = t + i * 1024;
            int pa_ = pos_agent[a];
            u32 ha = ((u32)pa_ * 2654435761u) >> 20;
            int fnd2 = 0;
            while (true) {
                int k = keyE[ha];
                if (k == pa_) { fnd2 = 1; break; }
                if (k == -1) break;
                ha = (ha + 1) & 4095;
            }
            unm[a] = !fnd2;
        }
        __syncthreads();
        int f0 = unm[2 * t], f1 = unm[2 * t + 1];
        int cnt = f0 + f1;
        valA[t] = cnt;
        __syncthreads();
        for (int off = 1; off < 1024; off <<= 1) {
            int v = (t >= off) ? valA[t - off] : 0;
            __syncthreads();
            valA[t] += v;
            __syncthreads();
        }
        int pos = valA[t] - cnt;
        if (f0 && pos < NREM) remain[pos] = 2 * t;
        if (f1 && pos + f0 < NREM) remain[pos + f0] = 2 * t + 1;
    } else if (b <= 128) {
        int g = ((b - 1) * 1024 + t) * 8;
        int s = 0;
#pragma unroll
        for (int i = 1; i < 7; ++i) s += (g >= woff[i]);
        const float* src = wp.p[s] + (g - woff[s]);
        float4 f0 = *(const float4*)(src);
        float4 f1 = *(const float4*)(src + 4);
        uint4 o;
        o.x = pk_bf16(f0.x, f0.y); o.y = pk_bf16(f0.z, f0.w);
        o.z = pk_bf16(f1.x, f1.y); o.w = pk_bf16(f1.z, f1.w);
        *(uint4*)(wb + g) = o;
    } else {
        int tt = (b - 129) * 1024 + t;
        int j = tt >> 5, c8 = tt & 31;
        const float* src = (j < LE) ? (x_ego + (size_t)j * CDIM)
                                    : (x_agent + (size_t)(j - LE) * CDIM);
        float4 f0 = *(const float4*)(src + c8 * 8);
        float4 f1 = *(const float4*)(src + c8 * 8 + 4);
        uint4 o;
        o.x = pk_bf16(f0.x, f0.y); o.y = pk_bf16(f0.z, f0.w);
        o.z = pk_bf16(f1.x, f1.y); o.w = pk_bf16(f1.z, f1.w);
        *(uint4*)(kv_b + (size_t)j * CDIM + c8 * 8) = o;
    }
}

// --- k_fmlp: fused 3-layer fusion MLP, 16 rows/block, h1/h2 in LDS --------
// blocks 0..127: MLP rows 0..2047; blocks 128..143: gather rows 2048..3071.
__global__ __launch_bounds__(256) void k_fmlp(const float* __restrict__ x_ego,
                                              const float* __restrict__ x_agent,
                                              const int* __restrict__ afe,
                                              const int* __restrict__ matched,
                                              const int* __restrict__ remain,
                                              const u16* __restrict__ Wf1_b,
                                              const u16* __restrict__ Wf2_b,
                                              const u16* __restrict__ Wf3_b,
                                              const float* __restrict__ bf1,
                                              const float* __restrict__ bf2,
                                              const float* __restrict__ bf3,
                                              float* __restrict__ qbuf,
                                              u16* __restrict__ qbuf_b) {
    const int blk = blockIdx.x;
    const int tid = threadIdx.x;
    if (blk >= 128) {  // gather blocks
        int rb = (blk - 128) * 64 + (tid >> 2);
        int row = LE + rb;
        int col = (tid & 3) * 64;
        int idx = remain[rb];
        idx = min(max(idx, 0), LA - 1);
        const float* src = x_agent + (size_t)idx * CDIM + col;
        float* dq = qbuf + (size_t)row * CDIM + col;
        u16* db = qbuf_b + (size_t)row * CDIM + col;
#pragma unroll
        for (int i = 0; i < 16; ++i) {
            float4 v = *(const float4*)(src + i * 4);
            *(float4*)(dq + i * 4) = v;
            *(uint2*)(db + i * 4) = make_uint2(pk_bf16(v.x, v.y), pk_bf16(v.z, v.w));
        }
        return;
    }
    __shared__ u16 h1[16 * 256];  // XOR-swizzled
    __shared__ u16 h2[16 * 256];
    const int w = tid >> 6, lane = tid & 63, quad = lane >> 4, qi = lane & 15;
    const int R0 = blk * 16;
    const int rg = R0 + qi;
    // stage 1: h1 = relu([x_ego | x_agent[afe]] @ Wf1^T + bf1)
    {
        const float* pe = x_ego + (size_t)rg * CDIM + quad * 8;
        const float* pg = x_agent + (size_t)afe[rg] * CDIM + quad * 8;
        f32x4 acc[4] = {};
        const u16* pb = Wf1_b + (size_t)(w * 64 + qi) * 512 + quad * 8;
#pragma unroll
        for (int kk = 0; kk < 256; kk += 32) {
            bf16x8 a = ld_pack8(pe + kk);
#pragma unroll
            for (int j = 0; j < 4; ++j) {
                bf16x8 bfr = *(const bf16x8*)(pb + (size_t)j * 16 * 512 + kk);
                acc[j] = MFMA(a, bfr, acc[j], 0, 0, 0);
            }
        }
#pragma unroll
        for (int kk = 0; kk < 256; kk += 32) {
            bf16x8 a = ld_pack8(pg + kk);
#pragma unroll
            for (int j = 0; j < 4; ++j) {
                bf16x8 bfr = *(const bf16x8*)(pb + (size_t)j * 16 * 512 + 256 + kk);
                acc[j] = MFMA(a, bfr, acc[j], 0, 0, 0);
            }
        }
#pragma unroll
        for (int j = 0; j < 4; ++j) {
            int col = w * 64 + j * 16 + qi;
            float bs = bf1[col];
#pragma unroll
            for (int r = 0; r < 4; ++r) {
                int row = quad * 4 + r;
                float v = fmaxf(acc[j][r] + bs, 0.f);
                int byte = (row * 512 + col * 2) ^ ((row & 7) << 4);
                *(u16*)((char*)h1 + byte) = bf16_1(v);
            }
        }
    }
    __syncthreads();
    // stage 2: h2 = relu(h1 @ Wf2^T + bf2)
    {
        f32x4 acc[4] = {};
        const u16* pb = Wf2_b + (size_t)(w * 64 + qi) * 256 + quad * 8;
#pragma unroll
        for (int kk = 0; kk < 256; kk += 32) {
            int byte = (qi * 512 + (kk + quad * 8) * 2) ^ ((qi & 7) << 4);
            bf16x8 a = *(const bf16x8*)((char*)h1 + byte);
#pragma unroll
            for (int j = 0; j < 4; ++j) {
                bf16x8 bfr = *(const bf16x8*)(pb + (size_t)j * 16 * 256 + kk);
                acc[j] = MFMA(a, bfr, acc[j], 0, 0, 0);
            }
        }
#pragma unroll
        for (int j = 0; j < 4; ++j) {
            int col = w * 64 + j * 16 + qi;
            float bs = bf2[col];
#pragma unroll
            for (int r = 0; r < 4; ++r) {
                int row = quad * 4 + r;
                float v = fmaxf(acc[j][r] + bs, 0.f);
                int byte = (row * 512 + col * 2) ^ ((row & 7) << 4);
                *(u16*)((char*)h2 + byte) = bf16_1(v);
            }
        }
    }
    __syncthreads();
    // stage 3: fused = h2 @ Wf3^T + bf3; select(matched); emit qbuf/qbuf_b
    {
        f32x4 acc[4] = {};
        const u16* pb = Wf3_b + (size_t)(w * 64 + qi) * 256 + quad * 8;
#pragma unroll
        for (int kk = 0; kk < 256; kk += 32) {
            int byte = (qi * 512 + (kk + quad * 8) * 2) ^ ((qi & 7) << 4);
            bf16x8 a = *(const bf16x8*)((char*)h2 + byte);
#pragma unroll
            for (int j = 0; j < 4; ++j) {
                bf16x8 bfr = *(const bf16x8*)(pb + (size_t)j * 16 * 256 + kk);
                acc[j] = MFMA(a, bfr, acc[j], 0, 0, 0);
            }
        }
        int m[4];
#pragma unroll
        for (int r = 0; r < 4; ++r) m[r] = matched[R0 + quad * 4 + r];
#pragma unroll
        for (int j = 0; j < 4; ++j) {
            int col = w * 64 + j * 16 + qi;
            float bs = bf3[col];
#pragma unroll
            for (int r = 0; r < 4; ++r) {
                int row = R0 + quad * 4 + r;
                float v = acc[j][r] + bs;
                if (!m[r]) v = x_ego[(size_t)row * CDIM + col];
                qbuf[(size_t)row * CDIM + col] = v;
                qbuf_b[(size_t)row * CDIM + col] = bf16_1(v);
            }
        }
    }
}

// --------------------------------------------------------- bf16 MFMA GEMM --
// EPI: 0=f32, 1=bf16 ; 64x64 tiles, 4 waves
template <int EPI, bool RELU>
__global__ __launch_bounds__(256) void gemm_bf16(const u16* __restrict__ A,
                                                 const u16* __restrict__ B,
                                                 const float* __restrict__ bias,
                                                 void* __restrict__ C,
                                                 int M, int N, int K) {
    const int tid = threadIdx.x;
    const int w = tid >> 6, lane = tid & 63;
    const int quad = lane >> 4, qi = lane & 15;
    const int wm = w >> 1, wn = w & 1;
    int bm, bn;
    xcd_tile(bm, bn);

    const u16* pa0 = A + (size_t)(bm + wm * 32 + qi) * K + quad * 8;
    const u16* pa1 = pa0 + (size_t)16 * K;
    const u16* pb0 = B + (size_t)(bn + wn * 32 + qi) * K + quad * 8;
    const u16* pb1 = pb0 + (size_t)16 * K;

    f32x4 acc00 = {0.f, 0.f, 0.f, 0.f}, acc01 = {0.f, 0.f, 0.f, 0.f};
    f32x4 acc10 = {0.f, 0.f, 0.f, 0.f}, acc11 = {0.f, 0.f, 0.f, 0.f};

#pragma unroll 4
    for (int k = 0; k < K; k += 32) {
        bf16x8 a0 = *(const bf16x8*)(pa0 + k);
        bf16x8 a1 = *(const bf16x8*)(pa1 + k);
        bf16x8 b0 = *(const bf16x8*)(pb0 + k);
        bf16x8 b1 = *(const bf16x8*)(pb1 + k);
        acc00 = MFMA(a0, b0, acc00, 0, 0, 0);
        acc01 = MFMA(a0, b1, acc01, 0, 0, 0);
        acc10 = MFMA(a1, b0, acc10, 0, 0, 0);
        acc11 = MFMA(a1, b1, acc11, 0, 0, 0);
    }

#pragma unroll
    for (int i = 0; i < 2; ++i) {
#pragma unroll
        for (int j = 0; j < 2; ++j) {
            f32x4 acc = (i == 0) ? (j == 0 ? acc00 : acc01) : (j == 0 ? acc10 : acc11);
            int n = bn + wn * 32 + j * 16 + qi;
            int mbase = bm + wm * 32 + i * 16 + quad * 4;
            float bs = bias[n];
            float v[4];
#pragma unroll
            for (int r = 0; r < 4; ++r) {
                float x = acc[r] + bs;
                if (RELU) x = fmaxf(x, 0.f);
                v[r] = x;
            }
            if (EPI == 0) {
                float* Cf = (float*)C;
#pragma unroll
                for (int r = 0; r < 4; ++r) Cf[(size_t)(mbase + r) * N + n] = v[r];
            } else {
                u16* Cb = (u16*)C;
#pragma unroll
                for (int r = 0; r < 4; ++r) Cb[(size_t)(mbase + r) * N + n] = bf16_1(v[r]);
            }
        }
    }
}

// --- gemm32: 32x64 tiles, 4 waves (wave = 16 rows x 32 cols), f32 out ------
__global__ __launch_bounds__(256) void gemm32(const u16* __restrict__ A,
                                              const u16* __restrict__ B,
                                              const float* __restrict__ bias,
                                              float* __restrict__ C,
                                              int M, int N, int K) {
    const int tid = threadIdx.x;
    const int w = tid >> 6, lane = tid & 63;
    const int quad = lane >> 4, qi = lane & 15;
    const int rh = w >> 1, ch = w & 1;
    int bm, bn;
    {
        int gx = gridDim.x;
        int tot = gx * gridDim.y;
        int p = blockIdx.y * gx + blockIdx.x;
        int l = p;
        if (!(tot & 7)) { int c = p & 7, s = p >> 3; l = c * (tot >> 3) + s; }
        bm = (l / gx) * 32;
        bn = (l % gx) * 64;
    }
    const u16* pa = A + (size_t)(bm + rh * 16 + qi) * K + quad * 8;
    const u16* pb0 = B + (size_t)(bn + ch * 32 + qi) * K + quad * 8;
    const u16* pb1 = pb0 + (size_t)16 * K;

    f32x4 acc0 = {0.f, 0.f, 0.f, 0.f}, acc1 = {0.f, 0.f, 0.f, 0.f};
#pragma unroll 8
    for (int k = 0; k < K; k += 32) {
        bf16x8 a = *(const bf16x8*)(pa + k);
        bf16x8 b0 = *(const bf16x8*)(pb0 + k);
        bf16x8 b1 = *(const bf16x8*)(pb1 + k);
        acc0 = MFMA(a, b0, acc0, 0, 0, 0);
        acc1 = MFMA(a, b1, acc1, 0, 0, 0);
    }
#pragma unroll
    for (int j = 0; j < 2; ++j) {
        f32x4 acc = j == 0 ? acc0 : acc1;
        int n = bn + ch * 32 + j * 16 + qi;
        int mbase = bm + rh * 16 + quad * 4;
        float bs = bias[n];
#pragma unroll
        for (int r = 0; r < 4; ++r)
            C[(size_t)(mbase + r) * N + n] = acc[r] + bs;
    }
}

// --------------------------- fused QKV projection (one dispatch) -----------
__global__ __launch_bounds__(256) void k_qkv(const u16* __restrict__ qbuf_b,
                                             const u16* __restrict__ kv_b,
                                             const u16* __restrict__ Wq,
                                             const u16* __restrict__ Wkv,
                                             const float* __restrict__ bqkv,
                                             u16* __restrict__ qb,
                                             u16* __restrict__ kbp,
                                             u16* __restrict__ vtb,
                                             float qscale) {
    int b;
    {
        int p = blockIdx.x;  // grid = 704 = 8 * 88
        int c = p & 7, s = p >> 3;
        b = c * 88 + s;
    }
    const u16 *A, *B;
    const float* bias;
    int bm, bn, mode;
    if (b < 192) {
        A = qbuf_b; B = Wq; bias = bqkv;
        bm = (b >> 2) * 64; bn = (b & 3) * 64; mode = 0;
    } else {
        int c = b - 192;
        A = kv_b; B = Wkv; bias = bqkv + 256;
        bm = (c >> 3) * 64; bn = (c & 7) * 64; mode = 1;
    }
    const int tid = threadIdx.x;
    const int w = tid >> 6, lane = tid & 63;
    const int quad = lane >> 4, qi = lane & 15;
    const int wm = w >> 1, wn = w & 1;
    const int K = 256;

    const u16* pa0 = A + (size_t)(bm + wm * 32 + qi) * K + quad * 8;
    const u16* pa1 = pa0 + (size_t)16 * K;
    const u16* pb0 = B + (size_t)(bn + wn * 32 + qi) * K + quad * 8;
    const u16* pb1 = pb0 + (size_t)16 * K;

    f32x4 acc00 = {0.f, 0.f, 0.f, 0.f}, acc01 = {0.f, 0.f, 0.f, 0.f};
    f32x4 acc10 = {0.f, 0.f, 0.f, 0.f}, acc11 = {0.f, 0.f, 0.f, 0.f};
#pragma unroll 4
    for (int k = 0; k < 256; k += 32) {
        bf16x8 a0 = *(const bf16x8*)(pa0 + k);
        bf16x8 a1 = *(const bf16x8*)(pa1 + k);
        bf16x8 b0 = *(const bf16x8*)(pb0 + k);
        bf16x8 b1 = *(const bf16x8*)(pb1 + k);
        acc00 = MFMA(a0, b0, acc00, 0, 0, 0);
        acc01 = MFMA(a0, b1, acc01, 0, 0, 0);
        acc10 = MFMA(a1, b0, acc10, 0, 0, 0);
        acc11 = MFMA(a1, b1, acc11, 0, 0, 0);
    }
#pragma unroll
    for (int i = 0; i < 2; ++i) {
#pragma unroll
        for (int j = 0; j < 2; ++j) {
            f32x4 acc = (i == 0) ? (j == 0 ? acc00 : acc01) : (j == 0 ? acc10 : acc11);
            int n = bn + wn * 32 + j * 16 + qi;
            int mbase = bm + wm * 32 + i * 16 + quad * 4;
            float bs = bias[n];
            float v[4];
#pragma unroll
            for (int r = 0; r < 4; ++r) v[r] = acc[r] + bs;
            if (mode == 0) {
#pragma unroll
                for (int r = 0; r < 4; ++r)
                    qb[(size_t)(mbase + r) * 256 + n] = bf16_1(v[r] * qscale);
            } else if (n < 256) {
#pragma unroll
                for (int r = 0; r < 4; ++r)
                    kbp[(size_t)(mbase + r) * 256 + n] = bf16_1(v[r]);
            } else {
                ushort4 o4;
                o4.x = bf16_1(v[0]); o4.y = bf16_1(v[1]);
                o4.z = bf16_1(v[2]); o4.w = bf16_1(v[3]);
                *(ushort4*)(vtb + (size_t)(n - 256) * LKC + mbase) = o4;
            }
        }
    }
}

// --------------------------- MFMA attention, LDS-staged K/V tiles ----------
__global__ __launch_bounds__(256) void attn_mfma(const u16* __restrict__ qb,
                                                 const u16* __restrict__ kb,
                                                 const u16* __restrict__ vtb,
                                                 float* __restrict__ Pl,
                                                 u16* __restrict__ Pacc) {
    __shared__ u16 Kt[2][64 * 32];
    __shared__ u16 Vt[2][32 * 64];
    __shared__ u16 plds[4][16 * 64];
    const int tid = threadIdx.x;
    const int w = tid >> 6, lane = tid & 63;
    const int quad = lane >> 4, qi = lane & 15;
    int h, ks, q0;
    {
        int p = (blockIdx.z * gridDim.y + blockIdx.y) * gridDim.x + blockIdx.x;
        int c = p & 7, s = p >> 3;
        int l = c * 384 + s;  // 3072 / 8
        int qblk = l % 48;
        int hk = l / 48;
        h = hk & 7; ks = hk >> 3;
        q0 = qblk * 64 + w * 16;
    }

    bf16x8 qf = *(const bf16x8*)(qb + (size_t)(q0 + qi) * CDIM + h * DH + quad * 8);

    f32x4 O0 = {0.f, 0.f, 0.f, 0.f}, O1 = {0.f, 0.f, 0.f, 0.f};
    float lsum = 0.f;

    const int krow = w * 16 + (lane >> 2), kcp = lane & 3;
    const int kc = kcp ^ (krow & 3);
    const u16* kg0 = kb + (size_t)krow * CDIM + h * DH + kc * 8;
    const int kdst = krow * 32 + kcp * 8;
    const int vd = w * 8 + (lane >> 3), vcp = lane & 7;
    const int vc = vcp ^ (vd & 7);
    const u16* vg0 = vtb + (size_t)(h * DH + vd) * LKC + vc * 8;
    const int vdst = vd * 64 + vcp * 8;

    const int ka0 = qi * 32 + ((quad ^ (qi & 3)) << 3);
    const int v00o = qi * 64 + ((quad ^ (qi & 7)) << 3);
    const int v01o = qi * 64 + (((quad + 4) ^ (qi & 7)) << 3);
    const int swz = (qi & 7);
    const int rd0 = qi * 64 + ((quad ^ swz) << 3);
    const int rd1 = qi * 64 + (((4 + quad) ^ swz) << 3);
    const int half = (quad & 1) << 2;

    int kt = ks * (LKC / KSPLIT);
    {
        bf16x8 kr = *(const bf16x8*)(kg0 + (size_t)kt * CDIM);
        bf16x8 vr = *(const bf16x8*)(vg0 + kt);
        *(bf16x8*)&Kt[0][kdst] = kr;
        *(bf16x8*)&Vt[0][vdst] = vr;
    }
    int buf = 0;
    for (int it = 0; it < NIT; ++it, kt += 64) {
        __syncthreads();
        bf16x8 knext, vnext;
        const bool more = (it + 1 < NIT);
        if (more) {
            knext = *(const bf16x8*)(kg0 + (size_t)(kt + 64) * CDIM);
            vnext = *(const bf16x8*)(vg0 + kt + 64);
        }

        bf16x8 a0 = *(const bf16x8*)&Kt[buf][ka0];
        bf16x8 a1 = *(const bf16x8*)&Kt[buf][ka0 + 16 * 32];
        bf16x8 a2 = *(const bf16x8*)&Kt[buf][ka0 + 32 * 32];
        bf16x8 a3 = *(const bf16x8*)&Kt[buf][ka0 + 48 * 32];
        f32x4 z = {0.f, 0.f, 0.f, 0.f};
        f32x4 s0 = MFMA(a0, qf, z, 0, 0, 0);
        f32x4 s1 = MFMA(a1, qf, z, 0, 0, 0);
        f32x4 s2 = MFMA(a2, qf, z, 0, 0, 0);
        f32x4 s3 = MFMA(a3, qf, z, 0, 0, 0);

        float p0[4], p1[4], p2[4], p3[4];
#pragma unroll
        for (int r = 0; r < 4; ++r) {
            p0[r] = fast_exp2(s0[r]); p1[r] = fast_exp2(s1[r]);
            p2[r] = fast_exp2(s2[r]); p3[r] = fast_exp2(s3[r]);
            lsum += p0[r] + p1[r] + p2[r] + p3[r];
        }

        u16* pb = &plds[w][0];
#pragma unroll
        for (int t2 = 0; t2 < 4; ++t2) {
            int jg = t2 * 2 + (quad >> 1);
            int off = qi * 64 + ((jg ^ swz) << 3) + half;
            uint2 pw;
            float* pp = (t2 == 0) ? p0 : (t2 == 1) ? p1 : (t2 == 2) ? p2 : p3;
            pw.x = pk_bf16(pp[0], pp[1]);
            pw.y = pk_bf16(pp[2], pp[3]);
            *(uint2*)&pb[off] = pw;
        }
        bf16x8 pa0 = *(bf16x8*)&pb[rd0];
        bf16x8 pa1 = *(bf16x8*)&pb[rd1];

        bf16x8 v00 = *(const bf16x8*)&Vt[buf][v00o];
        bf16x8 v01 = *(const bf16x8*)&Vt[buf][v01o];
        bf16x8 v10 = *(const bf16x8*)&Vt[buf][v00o + 16 * 64];
        bf16x8 v11 = *(const bf16x8*)&Vt[buf][v01o + 16 * 64];
        O0 = MFMA(pa0, v00, O0, 0, 0, 0);
        O0 = MFMA(pa1, v01, O0, 0, 0, 0);
        O1 = MFMA(pa0, v10, O1, 0, 0, 0);
        O1 = MFMA(pa1, v11, O1, 0, 0, 0);

        if (more) {
            *(bf16x8*)&Kt[buf ^ 1][kdst] = knext;
            *(bf16x8*)&Vt[buf ^ 1][vdst] = vnext;
        }
        buf ^= 1;
    }

    lsum += __shfl_xor(lsum, 16, 64);
    lsum += __shfl_xor(lsum, 32, 64);

    int pbase = (h * KSPLIT + ks) * LQC + q0;
    if (quad == 0) Pl[pbase + qi] = lsum;
#pragma unroll
    for (int r = 0; r < 4; ++r) {
        int q = quad * 4 + r;
        u16* pa = Pacc + (size_t)(pbase + q) * 32;
        pa[qi] = __builtin_bit_cast(u16, (_Float16)O0[r]);
        pa[16 + qi] = __builtin_bit_cast(u16, (_Float16)O1[r]);
    }
}

// --- k_oln: combine(Pacc/Pl) + out-proj + residual + LN1, 16 rows/block ----
__global__ __launch_bounds__(256) void k_oln(const float* __restrict__ Pl,
                                             const u16* __restrict__ Pacc,
                                             const u16* __restrict__ Wo_b,
                                             const float* __restrict__ bo,
                                             const float* __restrict__ qbuf,
                                             const float* __restrict__ g1,
                                             const float* __restrict__ be1,
                                             float* __restrict__ yq,
                                             u16* __restrict__ yq_b) {
    __shared__ u16 At[16 * 256];       // combined attn out, bf16, XOR-swizzled
    __shared__ float red[16][4][2];    // [row][wave][(s,sq)]
    const int tid = threadIdx.x;
    const int R0 = blockIdx.x * 16;
    // phase A: KSPLIT combine -> At
    {
        int row = tid >> 4, cg = tid & 15;
        int h = cg >> 1, dh = (cg & 1) * 16;
        int r = R0 + row;
        float L = 0.f;
        float o[16] = {};
#pragma unroll
        for (int ks = 0; ks < 8; ++ks) {
            size_t pidx = (size_t)(h * 8 + ks) * LQC + r;
            L += Pl[pidx];
            const u16* pa = Pacc + pidx * 32 + dh;
            f16x8 v0 = *(const f16x8*)(pa);
            f16x8 v1 = *(const f16x8*)(pa + 8);
#pragma unroll
            for (int i = 0; i < 8; ++i) {
                o[i] += (float)v0[i];
                o[8 + i] += (float)v1[i];
            }
        }
        float invL = 1.0f / L;
        int cb = h * 32 + dh;
#pragma unroll
        for (int i = 0; i < 8; ++i) {
            int c0 = cb + 2 * i;
            u32 pk = pk_bf16(o[2 * i] * invL, o[2 * i + 1] * invL);
            int byte = (row * 512 + c0 * 2) ^ ((row & 7) << 4);
            *(u32*)((char*)At + byte) = pk;
        }
    }
    __syncthreads();
    // phase B: GEMM (K=256), wave w covers cols w*64..w*64+63
    const int w = tid >> 6, lane = tid & 63, quad = lane >> 4, qi = lane & 15;
    f32x4 acc[4] = {};
    const u16* pb = Wo_b + (size_t)(w * 64 + qi) * 256 + quad * 8;
#pragma unroll
    for (int kk = 0; kk < 256; kk += 32) {
        int byte = (qi * 512 + (kk + quad * 8) * 2) ^ ((qi & 7) << 4);
        bf16x8 a = *(const bf16x8*)((char*)At + byte);
#pragma unroll
        for (int j = 0; j < 4; ++j) {
            bf16x8 bfr = *(const bf16x8*)(pb + (size_t)j * 16 * 256 + kk);
            acc[j] = MFMA(a, bfr, acc[j], 0, 0, 0);
        }
    }
    // phase C: +bias +residual, LN1 (intra-block reduce), emit yq/yq_b
    float v[4][4], s[4] = {}, sq[4] = {};
#pragma unroll
    for (int j = 0; j < 4; ++j) {
        int col = w * 64 + j * 16 + qi;
        float bs = bo[col];
#pragma unroll
        for (int r = 0; r < 4; ++r) {
            int row = R0 + quad * 4 + r;
            float x = acc[j][r] + bs + qbuf[(size_t)row * CDIM + col];
            v[j][r] = x; s[r] += x; sq[r] += x * x;
        }
    }
#pragma unroll
    for (int off = 1; off < 16; off <<= 1) {
#pragma unroll
        for (int r = 0; r < 4; ++r) {
            s[r] += __shfl_xor(s[r], off, 64);
            sq[r] += __shfl_xor(sq[r], off, 64);
        }
    }
    if (qi == 0) {
#pragma unroll
        for (int r = 0; r < 4; ++r) {
            red[quad * 4 + r][w][0] = s[r];
            red[quad * 4 + r][w][1] = sq[r];
        }
    }
    __syncthreads();
    float mean[4], rstd[4];
#pragma unroll
    for (int r = 0; r < 4; ++r) {
        int rl = quad * 4 + r;
        float st = red[rl][0][0] + red[rl][1][0] + red[rl][2][0] + red[rl][3][0];
        float sqt = red[rl][0][1] + red[rl][1][1] + red[rl][2][1] + red[rl][3][1];
        mean[r] = st * (1.f / 256.f);
        float var = sqt * (1.f / 256.f) - mean[r] * mean[r];
        rstd[r] = rsqrtf(var + 1e-5f);
    }
#pragma unroll
    for (int j = 0; j < 4; ++j) {
        int col = w * 64 + j * 16 + qi;
        float gg = g1[col], bb = be1[col];
#pragma unroll
        for (int r = 0; r < 4; ++r) {
            int row = R0 + quad * 4 + r;
            float o = (v[j][r] - mean[r]) * rstd[r] * gg + bb;
            yq[(size_t)row * CDIM + col] = o;
            yq_b[(size_t)row * CDIM + col] = bf16_1(o);
        }
    }
}

// -------------------------------------------------------------- layernorm --
template <bool EMIT_BF16>
__global__ __launch_bounds__(256) void ln_kernel(const float* __restrict__ X,
                                                 const float* __restrict__ R,
                                                 const float* __restrict__ g,
                                                 const float* __restrict__ b,
                                                 float* __restrict__ out,
                                                 u16* __restrict__ out_b) {
    int lane = threadIdx.x & 63;
    int row = blockIdx.x * 4 + (threadIdx.x >> 6);
    const float* x = X + (size_t)row * CDIM;
    const float* r = R + (size_t)row * CDIM;
    float4 xv = *(const float4*)(x + lane * 4);
    float4 rv = *(const float4*)(r + lane * 4);
    float v[4] = {xv.x + rv.x, xv.y + rv.y, xv.z + rv.z, xv.w + rv.w};
    float s = v[0] + v[1] + v[2] + v[3];
    float sq = v[0] * v[0] + v[1] * v[1] + v[2] * v[2] + v[3] * v[3];
#pragma unroll
    for (int off = 32; off >= 1; off >>= 1) {
        s += __shfl_xor(s, off, 64);
        sq += __shfl_xor(sq, off, 64);
    }
    float mean = s * (1.f / 256.f);
    float var = sq * (1.f / 256.f) - mean * mean;
    float rstd = rsqrtf(var + 1e-5f);
    float4 gv = *(const float4*)(g + lane * 4);
    float4 bv = *(const float4*)(b + lane * 4);
    float4 o = make_float4((v[0] - mean) * rstd * gv.x + bv.x,
                           (v[1] - mean) * rstd * gv.y + bv.y,
                           (v[2] - mean) * rstd * gv.z + bv.z,
                           (v[3] - mean) * rstd * gv.w + bv.w);
    *(float4*)(out + (size_t)row * CDIM + lane * 4) = o;
    if (EMIT_BF16) {
        uint2 ob;
        ob.x = pk_bf16(o.x, o.y);
        ob.y = pk_bf16(o.z, o.w);
        *(uint2*)(out_b + (size_t)row * CDIM + lane * 4) = ob;
    }
}

// ------------------------------------------------------------------ launch --
extern "C" void kernel_launch(void* const* d_in, const int* in_sizes, int n_in,
                              void* d_out, int out_size, void* d_ws, size_t ws_size,
                              hipStream_t stream) {
    const float* x_ego = (const float*)d_in[0];
    const float* x_agent = (const float*)d_in[1];
    const float* Wf1 = (const float*)d_in[2];
    const float* bf1 = (const float*)d_in[3];
    const float* Wf2 = (const float*)d_in[4];
    const float* bf2 = (const float*)d_in[5];
    const float* Wf3 = (const float*)d_in[6];
    const float* bf3 = (const float*)d_in[7];
    const float* Wqkv = (const float*)d_in[8];
    const float* bqkv = (const float*)d_in[9];
    const float* Wo = (const float*)d_in[10];
    const float* bo = (const float*)d_in[11];
    const float* W1 = (const float*)d_in[12];
    const float* b1 = (const float*)d_in[13];
    const float* W2 = (const float*)d_in[14];
    const float* b2 = (const float*)d_in[15];
    const float* g1 = (const float*)d_in[16];
    const float* be1 = (const float*)d_in[17];
    const float* g2 = (const float*)d_in[18];
    const float* be2 = (const float*)d_in[19];
    const int* pos_ego = (const int*)d_in[20];
    const int* pos_agent = (const int*)d_in[21];

    float* ws = (float*)d_ws;
    size_t o = 0;
    float* qbuf = ws + o; o += 786432;
    float* yq = ws + o; o += 786432;
    float* ff2 = ws + o; o += 786432;
    float* Pl = ws + o; o += HN * KSPLIT * LQC;                       // 196608
    u16* Pacc = (u16*)(ws + o); o += (size_t)HN * KSPLIT * LQC * 16;  // f16
    u16* wb = (u16*)(ws + o); o += 524288;        // 1,048,576 u16
    u16* qbuf_b = (u16*)(ws + o); o += 393216;    // LQC*256
    u16* kv_b = (u16*)(ws + o); o += 524288;      // LKC*256
    u16* qb = (u16*)(ws + o); o += 393216;
    u16* kb = (u16*)(ws + o); o += 524288;
    u16* vtb = (u16*)(ws + o); o += 524288;
    u16* yq_b = (u16*)(ws + o); o += 393216;
    u16* ff1_b = (u16*)(ws + o); o += 1572864;    // LQC*1024
    int* afe = (int*)(ws + o);
    int* matched = afe + LE;
    int* remain = matched + LE;

    const u16* Wf1_b = wb + 0;
    const u16* Wf2_b = wb + 131072;
    const u16* Wf3_b = wb + 196608;
    const u16* Wq_b = wb + 262144;
    const u16* Wkv_b = wb + 327680;
    const u16* Wo_b = wb + 458752;
    const u16* W1_b = wb + 524288;
    const u16* W2_b = wb + 786432;

    WPtrs wp;
    wp.p[0] = Wf1; wp.p[1] = Wf2; wp.p[2] = Wf3; wp.p[3] = Wqkv;
    wp.p[4] = Wo; wp.p[5] = W1; wp.p[6] = W2;

    // 1. match + scan co-dispatched with weight cvt + kv staging
    k_prep<<<257, 1024, 0, stream>>>(pos_ego, pos_agent, afe, matched, remain,
                                     x_ego, x_agent, wp, wb, kv_b);

    const float qscale = 0.17677669529663687f * 1.4426950408889634f;

    // 2. fused 3-layer fusion MLP + gather
    k_fmlp<<<144, 256, 0, stream>>>(x_ego, x_agent, afe, matched, remain,
                                    Wf1_b, Wf2_b, Wf3_b, bf1, bf2, bf3,
                                    qbuf, qbuf_b);

    // 3. fused QKV projections
    k_qkv<<<704, 256, 0, stream>>>(qbuf_b, kv_b, Wq_b, Wkv_b, bqkv, qb, kb, vtb, qscale);

    // 4. attention (KSPLIT=8)
    attn_mfma<<<dim3(LQC / 64, HN, KSPLIT), 256, 0, stream>>>(qb, kb, vtb, Pl, Pacc);

    // 5. combine + out-proj + residual + LN1
    k_oln<<<LQC / 16, 256, 0, stream>>>(Pl, Pacc, Wo_b, bo, qbuf, g1, be1, yq, yq_b);

    // 6. FFN1 (64x64 tiles, 768 blocks)
    gemm_bf16<1, true><<<dim3(16, 48), 256, 0, stream>>>(yq_b, W1_b, b1, ff1_b,
                                                         LQC, DFF, 256);
    // 7. FFN2 (32x64 tiles, 384 blocks)
    gemm32<<<dim3(4, 96), 256, 0, stream>>>(ff1_b, W2_b, b2, ff2, LQC, 256, DFF);
    // 8. LN2
    ln_kernel<false><<<LQC / 4, 256, 0, stream>>>(yq, ff2, g2, be2, (float*)d_out, nullptr);
}